// Round 1
// baseline (1319.128 us; speedup 1.0000x reference)
//
#include <hip/hip_runtime.h>
#include <math.h>
#include <stdint.h>

// ---------------------------------------------------------------------------
// Threefry2x32 (JAX-compatible) and gumbel mapping
// ---------------------------------------------------------------------------
__device__ __forceinline__ uint32_t rotl32(uint32_t v, int r) {
    return (v << r) | (v >> (32 - r));
}

__device__ __forceinline__ void threefry2x32(uint32_t k0, uint32_t k1,
                                             uint32_t& x0, uint32_t& x1) {
    uint32_t ks[3] = {k0, k1, k0 ^ k1 ^ 0x1BD11BDAu};
    const int rot[2][4] = {{13, 15, 26, 6}, {17, 29, 16, 24}};
    x0 += ks[0];
    x1 += ks[1];
#pragma unroll
    for (int i = 0; i < 5; ++i) {
#pragma unroll
        for (int r = 0; r < 4; ++r) {
            x0 += x1;
            x1 = rotl32(x1, rot[i & 1][r]);
            x1 ^= x0;
        }
        x0 += ks[(i + 1) % 3];
        x1 += ks[(i + 2) % 3] + (uint32_t)(i + 1);
    }
}

// JAX: uniform(key, minval=tiny, maxval=1.)  ->  gumbel = -log(-log(u))
__device__ __forceinline__ float gumbel_from_bits(uint32_t bits) {
    uint32_t fb = (bits >> 9) | 0x3f800000u;
    float u = __uint_as_float(fb) - 1.0f;
    const float tiny = 1.1754943508222875e-38f;
    u = u * (1.0f - tiny) + tiny;   // (1-tiny) rounds to 1.0f; only u==0 changes
    u = fmaxf(tiny, u);
    return -logf(-logf(u));
}

__device__ __forceinline__ float softplus_f(float x) {
    return fmaxf(x, 0.0f) + log1pf(expf(-fabsf(x)));
}

// ---------------------------------------------------------------------------
// GEMM: C = X * X^T   (n x n, K inner), f32 vector ALU, 128x128 tile, 8x8/thread
// ---------------------------------------------------------------------------
#define BM 128
#define BN 128
#define BKK 16

__global__ __launch_bounds__(256) void gemm_xxt(const float* __restrict__ X,
                                                float* __restrict__ C,
                                                int n, int K) {
    __shared__ float As[BKK][BM];
    __shared__ float Bs[BKK][BN];
    const int tid = threadIdx.x;
    const int tx = tid & 15;   // 0..15  (col group)
    const int ty = tid >> 4;   // 0..15  (row group)
    const int bm = blockIdx.y * BM;
    const int bn = blockIdx.x * BN;

    float acc[8][8];
#pragma unroll
    for (int p = 0; p < 8; ++p)
#pragma unroll
        for (int q = 0; q < 8; ++q) acc[p][q] = 0.0f;

    for (int k0 = 0; k0 < K; k0 += BKK) {
        for (int l = tid; l < BM * BKK / 4; l += 256) {
            int m = l >> 2;
            int kq = (l & 3) << 2;
            const float4 v = *(const float4*)(X + (size_t)(bm + m) * K + k0 + kq);
            As[kq + 0][m] = v.x; As[kq + 1][m] = v.y;
            As[kq + 2][m] = v.z; As[kq + 3][m] = v.w;
        }
        for (int l = tid; l < BN * BKK / 4; l += 256) {
            int m = l >> 2;
            int kq = (l & 3) << 2;
            const float4 v = *(const float4*)(X + (size_t)(bn + m) * K + k0 + kq);
            Bs[kq + 0][m] = v.x; Bs[kq + 1][m] = v.y;
            Bs[kq + 2][m] = v.z; Bs[kq + 3][m] = v.w;
        }
        __syncthreads();
#pragma unroll
        for (int kk = 0; kk < BKK; ++kk) {
            float a[8], b[8];
#pragma unroll
            for (int p = 0; p < 8; ++p) a[p] = As[kk][p * 16 + ty];
#pragma unroll
            for (int q = 0; q < 8; ++q) b[q] = Bs[kk][q * 16 + tx];
#pragma unroll
            for (int p = 0; p < 8; ++p)
#pragma unroll
                for (int q = 0; q < 8; ++q)
                    acc[p][q] = fmaf(a[p], b[q], acc[p][q]);
        }
        __syncthreads();
    }

    for (int p = 0; p < 8; ++p) {
        int r = bm + p * 16 + ty;
        for (int q = 0; q < 8; ++q) {
            C[(size_t)r * n + bn + q * 16 + tx] = acc[p][q];
        }
    }
}

// ---------------------------------------------------------------------------
// Per-row kernel: masks, bitonic sort of negatives, mean/std, gumbel top-7
// ---------------------------------------------------------------------------
#define SORT_N 4096

__global__ __launch_bounds__(256) void row_kernel(const float* __restrict__ sim,
                                                  float* __restrict__ row_out,
                                                  int n, int k, long long H) {
    const int row = blockIdx.x;
    const int tid = threadIdx.x;
    const int NEG = n - k;

    __shared__ float vals[SORT_N];    // negatives (sorted), + INF pad
    __shared__ float scores[SORT_N];  // log_prob + gumbel
    __shared__ float rv[256];
    __shared__ int ri[256];
    __shared__ float pos_s[32];       // k <= 32

    const float* simrow = sim + (size_t)row * n;
    const int base = (row / k) * k;

    // scatter columns into positives / negatives (column order)
    for (int j = tid; j < n; j += 256) {
        float v = simrow[j];
        if (j >= base && j < base + k) {
            pos_s[j - base] = v;  // self slot included, skipped later
        } else {
            int slot = (j < base) ? j : j - k;
            vals[slot] = v;
        }
    }
    for (int j = NEG + tid; j < SORT_N; j += 256) vals[j] = INFINITY;
    __syncthreads();

    // bitonic sort ascending over SORT_N
    for (int kk = 2; kk <= SORT_N; kk <<= 1) {
        for (int jj = kk >> 1; jj > 0; jj >>= 1) {
            for (int idx = tid; idx < SORT_N; idx += 256) {
                int p = idx ^ jj;
                if (p > idx) {
                    float a = vals[idx];
                    float b = vals[p];
                    bool asc = ((idx & kk) == 0);
                    if ((a > b) == asc) {
                        vals[idx] = b;
                        vals[p] = a;
                    }
                }
            }
            __syncthreads();
        }
    }

    // mean (pass 1)
    float ps = 0.0f;
    for (int j = tid; j < NEG; j += 256) ps += vals[j];
    rv[tid] = ps;
    __syncthreads();
    for (int off = 128; off; off >>= 1) {
        if (tid < off) rv[tid] += rv[tid + off];
        __syncthreads();
    }
    const float neg_sum = rv[0];
    const float m = neg_sum / (float)NEG;
    __syncthreads();

    // variance (pass 2)
    float ps2 = 0.0f;
    for (int j = tid; j < NEG; j += 256) {
        float d = vals[j] - m;
        ps2 += d * d;
    }
    rv[tid] = ps2;
    __syncthreads();
    for (int off = 128; off; off >>= 1) {
        if (tid < off) rv[tid] += rv[tid + off];
        __syncthreads();
    }
    const float var = rv[0] / (float)NEG;
    const float sd = sqrtf(var);
    const float denom = 2.0f * (sd * sd);   // matches 2.0 * std**2
    __syncthreads();

    // scores = (v-m)^2/denom + gumbel(flat index)
    for (int j = tid; j < NEG; j += 256) {
        long long f = (long long)row * NEG + j;
        uint32_t x0, x1;
        bool lo = (f < H);
        if (lo) { x0 = (uint32_t)f;        x1 = (uint32_t)(f + H); }
        else    { x0 = (uint32_t)(f - H);  x1 = (uint32_t)f; }
        threefry2x32(0u, 42u, x0, x1);
        float g = gumbel_from_bits(lo ? x0 : x1);
        float d = vals[j] - m;
        scores[j] = (d * d) / denom + g;
    }
    __syncthreads();

    // top-(k-1) by repeated argmax, tie-break lower index (== lax.top_k order)
    float nl_sum = 0.0f;
    float neg_last = 0.0f;
    for (int t = 0; t < k - 1; ++t) {
        float bv = -INFINITY;
        int bi = 0x7fffffff;
        for (int j = tid; j < NEG; j += 256) {
            float s = scores[j];
            if (s > bv || (s == bv && j < bi)) { bv = s; bi = j; }
        }
        rv[tid] = bv;
        ri[tid] = bi;
        __syncthreads();
        for (int off = 128; off; off >>= 1) {
            if (tid < off) {
                float ov = rv[tid + off];
                int oi = ri[tid + off];
                if (ov > rv[tid] || (ov == rv[tid] && oi < ri[tid])) {
                    rv[tid] = ov;
                    ri[tid] = oi;
                }
            }
            __syncthreads();
        }
        int sel = ri[0];
        float v = vals[sel];
        nl_sum += softplus_f(50.0f * (v - 0.5f));
        if (t == k - 2) neg_last = v;
        __syncthreads();
        if (tid == 0) scores[sel] = -INFINITY;
        __syncthreads();
    }

    if (tid == 0) {
        float psum = 0.0f, pmax = -INFINITY, plos = 0.0f;
        for (int q = 0; q < k; ++q) {
            if (base + q == row) continue;
            float v = pos_s[q];
            psum += v;
            pmax = fmaxf(pmax, v);
            plos += softplus_f(-2.0f * (v - 0.5f));
        }
        float pos_loss = plos / (float)(k - 1);
        float neg_loss = 0.04f * (nl_sum / (float)(k - 1));
        row_out[row * 4 + 0] = pos_loss + neg_loss;
        row_out[row * 4 + 1] = (pmax > neg_last + 0.05f) ? 1.0f : 0.0f;
        row_out[row * 4 + 2] = psum;
        row_out[row * 4 + 3] = neg_sum;
    }
}

// ---------------------------------------------------------------------------
// Deterministic final reduction (single block, f64 accumulation)
// ---------------------------------------------------------------------------
__global__ __launch_bounds__(256) void reduce_kernel(const float* __restrict__ row_out,
                                                     float* __restrict__ out,
                                                     int n, int k) {
    __shared__ double sh[4][256];
    const int tid = threadIdx.x;
    double a = 0.0, b = 0.0, c = 0.0, d = 0.0;
    for (int i = tid; i < n; i += 256) {
        a += (double)row_out[i * 4 + 0];
        b += (double)row_out[i * 4 + 1];
        c += (double)row_out[i * 4 + 2];
        d += (double)row_out[i * 4 + 3];
    }
    sh[0][tid] = a; sh[1][tid] = b; sh[2][tid] = c; sh[3][tid] = d;
    __syncthreads();
    for (int off = 128; off; off >>= 1) {
        if (tid < off) {
            sh[0][tid] += sh[0][tid + off];
            sh[1][tid] += sh[1][tid + off];
            sh[2][tid] += sh[2][tid + off];
            sh[3][tid] += sh[3][tid + off];
        }
        __syncthreads();
    }
    if (tid == 0) {
        out[0] = (float)(sh[0][0] / (double)n);                      // loss
        out[1] = (float)(sh[1][0] / (double)n);                      // prec
        out[2] = (float)(sh[2][0] / ((double)n * (double)(k - 1)));  // pos_d
        out[3] = (float)(sh[3][0] / ((double)n * (double)(n - k)));  // neg_d
    }
}

// ---------------------------------------------------------------------------
extern "C" void kernel_launch(void* const* d_in, const int* in_sizes, int n_in,
                              void* d_out, int out_size, void* d_ws, size_t ws_size,
                              hipStream_t stream) {
    const float* X = (const float*)d_in[0];
    const int n = in_sizes[1];            // 4096
    const int K = in_sizes[0] / n;        // 1024
    const int k = 8;                      // num_instances (static in setup)

    float* sim = (float*)d_ws;
    float* row_out = (float*)((char*)d_ws + (size_t)n * n * sizeof(float));
    const long long H = ((long long)n * (long long)(n - k)) / 2;

    dim3 gg(n / BN, n / BM);
    gemm_xxt<<<gg, 256, 0, stream>>>(X, sim, n, K);
    row_kernel<<<n, 256, 0, stream>>>(sim, row_out, n, k, H);
    reduce_kernel<<<1, 256, 0, stream>>>(row_out, (float*)d_out, n, k);
}